// Round 14
// baseline (854.109 us; speedup 1.0000x reference)
//
#include <hip/hip_runtime.h>
#include <hip/hip_bf16.h>
#include <cstddef>

#define N_NODES 50000
#define E_EDGES 300000
#define D 256
#define SCHUNKS 196           // ceil(50001/256)

typedef unsigned short u16;
typedef __attribute__((ext_vector_type(8))) short bf16x8;   // 8 bf16 = 4 VGPRs
typedef __attribute__((ext_vector_type(8))) unsigned short us8;
typedef __attribute__((ext_vector_type(4))) float f32x4;

__device__ __forceinline__ float b2f(u16 u) {
    return __uint_as_float(((unsigned)u) << 16);
}
__device__ __forceinline__ u16 f2b(float f) {
    __hip_bfloat16 h = __float2bfloat16(f);
    return *reinterpret_cast<u16*>(&h);
}
__device__ __forceinline__ void async16(const u16* g, u16* l) {
    __builtin_amdgcn_global_load_lds(
        (const __attribute__((address_space(1))) void*)g,
        (__attribute__((address_space(3))) void*)l, 16, 0, 0);
}

// ---------------------------------------------------------------------------
// prep: pack weights to bf16 once.
//  Bfull[j][k] (1024x512):
//    k<256 : j<768 ? W_ih[j][k] : W_hh[j-256][k]     (rz + i_n + h_n rows)
//    k>=256: j<512 ? W_hh[j][k-256] : 0
//  Bcat1024[j][k] (256x1024) = W_{k>>8}[j][k&255]
//  bfull[1024] = j<512: b_ih+b_hh; 512-767: b_ih[j]; 768-1023: b_hh[j-256]
//  be4[e*256+k] = b_e[k]
// ---------------------------------------------------------------------------
__global__ __launch_bounds__(256) void prep_kernel(
    const float* __restrict__ W0, const float* __restrict__ W1,
    const float* __restrict__ W2, const float* __restrict__ W3,
    const float* __restrict__ b0, const float* __restrict__ b1,
    const float* __restrict__ b2, const float* __restrict__ b3,
    const float* __restrict__ W_ih, const float* __restrict__ W_hh,
    const float* __restrict__ b_ih, const float* __restrict__ b_hh,
    u16* __restrict__ Bfull_b, u16* __restrict__ Bcat_b,
    float* __restrict__ bfull, float* __restrict__ be4)
{
    int t = blockIdx.x * 256 + threadIdx.x;    // [0, 524288)
    {
        int j = t >> 9, k = t & 511;
        float v;
        if (k < 256) v = (j < 768) ? W_ih[j * 256 + k] : W_hh[(j - 256) * 256 + k];
        else         v = (j < 512) ? W_hh[j * 256 + (k - 256)] : 0.f;
        Bfull_b[t] = f2b(v);
    }
    if (t < 262144) {
        int j = t >> 10, k = t & 1023;
        int e = k >> 8, kk = k & 255;
        const float* W = (e == 0) ? W0 : (e == 1) ? W1 : (e == 2) ? W2 : W3;
        Bcat_b[t] = f2b(W[j * 256 + kk]);
    }
    if (t < 1024) {
        bfull[t] = (t < 512) ? b_ih[t] + b_hh[t]
                 : (t < 768) ? b_ih[t] : b_hh[t - 256];
        int e = t >> 8, k = t & 255;
        const float* b = (e == 0) ? b0 : (e == 1) ? b1 : (e == 2) ? b2 : b3;
        be4[t] = b[k];
    }
}

// x (f32) -> h_bf (bf16) once: the zone GEMM stages h via async16 (bf16 only)
__global__ __launch_bounds__(256) void xcvt_kernel(
    const float* __restrict__ x, u16* __restrict__ hb)
{
    int t = blockIdx.x * 256 + threadIdx.x;      // 4-elem slot
    float4 v = *reinterpret_cast<const float4*>(x + (size_t)t * 4);
    ushort4 o;
    o.x = f2b(v.x); o.y = f2b(v.y); o.z = f2b(v.z); o.w = f2b(v.w);
    *reinterpret_cast<ushort4*>(hb + (size_t)t * 4) = o;
}

// ---------------------------------------------------------------------------
// CSR build, rank-based (one atomic pass).
// ---------------------------------------------------------------------------
__global__ __launch_bounds__(256) void cnt_kernel(
    const int* __restrict__ d0, const int* __restrict__ d1,
    const int* __restrict__ d2, const int* __restrict__ d3,
    int* __restrict__ rowptr, u16* __restrict__ rank)
{
    int i = blockIdx.x * 256 + threadIdx.x;
    if (i >= 4 * E_EDGES) return;
    int e = i / E_EDGES;
    int k = i - e * E_EDGES;
    const int* dp = (e == 0) ? d0 : (e == 1) ? d1 : (e == 2) ? d2 : d3;
    rank[i] = (u16)atomicAdd(&rowptr[e * (N_NODES + 1) + dp[k] + 1], 1);
}

__global__ __launch_bounds__(256) void scan1_kernel(
    int* __restrict__ rowptr, int* __restrict__ bsum)
{
    int e = blockIdx.y;
    int blk = blockIdx.x;
    int t = threadIdx.x;
    int idx = blk * 256 + t;
    int* rp = rowptr + e * (N_NODES + 1);
    int v = (idx <= N_NODES) ? rp[idx] : 0;
    __shared__ int s[256];
    s[t] = v;
    __syncthreads();
    for (int o = 1; o < 256; o <<= 1) {
        int u = (t >= o) ? s[t - o] : 0;
        __syncthreads();
        s[t] += u;
        __syncthreads();
    }
    if (idx <= N_NODES) rp[idx] = s[t];
    if (t == 255) bsum[e * SCHUNKS + blk] = s[255];
}

__global__ __launch_bounds__(256) void scan2_kernel(int* __restrict__ bsum)
{
    int e = blockIdx.x;
    int t = threadIdx.x;
    int v = (t < SCHUNKS) ? bsum[e * SCHUNKS + t] : 0;
    __shared__ int s[256];
    s[t] = v;
    __syncthreads();
    for (int o = 1; o < 256; o <<= 1) {
        int u = (t >= o) ? s[t - o] : 0;
        __syncthreads();
        s[t] += u;
        __syncthreads();
    }
    if (t < SCHUNKS) bsum[e * SCHUNKS + t] = s[t];
}

__global__ __launch_bounds__(256) void scan3_kernel(
    int* __restrict__ rowptr, const int* __restrict__ bsum)
{
    int e = blockIdx.y;
    int blk = blockIdx.x;
    if (blk == 0) return;
    int idx = blk * 256 + threadIdx.x;
    if (idx > N_NODES) return;
    rowptr[e * (N_NODES + 1) + idx] += bsum[e * SCHUNKS + blk - 1];
}

__global__ __launch_bounds__(256) void fill_csr_kernel(
    const int* __restrict__ s0, const int* __restrict__ d0,
    const int* __restrict__ s1, const int* __restrict__ d1,
    const int* __restrict__ s2, const int* __restrict__ d2,
    const int* __restrict__ s3, const int* __restrict__ d3,
    const int* __restrict__ rowptr, const u16* __restrict__ rank,
    u16* __restrict__ colb, unsigned char* __restrict__ degmask)
{
    int i = blockIdx.x * 256 + threadIdx.x;
    if (i >= 4 * E_EDGES) return;
    int e = i / E_EDGES;
    int k = i - e * E_EDGES;
    const int* sp = (e == 0) ? s0 : (e == 1) ? s1 : (e == 2) ? s2 : s3;
    const int* dp = (e == 0) ? d0 : (e == 1) ? d1 : (e == 2) ? d2 : d3;
    int dst = dp[k];
    int slot = rowptr[e * (N_NODES + 1) + dst] + (int)rank[i];
    colb[(size_t)e * E_EDGES + slot] = (u16)sp[k];
    if (i < N_NODES) {
        int m = 0;
#pragma unroll
        for (int ee = 0; ee < 4; ++ee) {
            const int* rp = rowptr + ee * (N_NODES + 1);
            if (rp[i + 1] > rp[i]) m |= (1 << ee);
        }
        degmask[i] = (unsigned char)m;
    }
}

// ---------------------------------------------------------------------------
// gather: Hmean4[n][e*256+c] = mean over in-edges(e) of h[src][c]
// Half-wave edge pairing: lanes 0-31 = edge j, lanes 32-63 = edge j+1;
// each lane loads 16B (8 cols). 2-pair unroll -> 4 edges in flight.
// HF32: h is f32 (input x, step 0); else bf16 state.
// grid (N/2, 2); wave = (node, etype-slot).
// ---------------------------------------------------------------------------
template <int HF32>
__global__ __launch_bounds__(256) void gather_kernel(
    const void* __restrict__ hv, const int* __restrict__ rowptr,
    const u16* __restrict__ colb, u16* __restrict__ out)
{
    int p = blockIdx.y;
    int n = blockIdx.x * 2 + (threadIdx.x >> 7);
    int el = (threadIdx.x >> 6) & 1;
    int lane = threadIdx.x & 63;
    int half = lane >> 5;
    int hl = lane & 31;
    int e = p * 2 + el;
    const int* rp = rowptr + e * (N_NODES + 1);
    int beg = rp[n], end = rp[n + 1];
    const u16* cb = colb + (size_t)e * E_EDGES;

    float a[8] = {0.f, 0.f, 0.f, 0.f, 0.f, 0.f, 0.f, 0.f};
    float b[8] = {0.f, 0.f, 0.f, 0.f, 0.f, 0.f, 0.f, 0.f};

#define ACC_ROW(dst, src)                                                     \
    do {                                                                      \
        if (HF32) {                                                           \
            const float* hp = (const float*)hv + (size_t)(src) * D + hl * 8;  \
            float4 v0 = *reinterpret_cast<const float4*>(hp);                 \
            float4 v1 = *reinterpret_cast<const float4*>(hp + 4);             \
            dst[0] += v0.x; dst[1] += v0.y; dst[2] += v0.z; dst[3] += v0.w;   \
            dst[4] += v1.x; dst[5] += v1.y; dst[6] += v1.z; dst[7] += v1.w;   \
        } else {                                                              \
            us8 u = *reinterpret_cast<const us8*>(                            \
                (const u16*)hv + (size_t)(src) * D + hl * 8);                 \
            dst[0] += b2f(u[0]); dst[1] += b2f(u[1]);                         \
            dst[2] += b2f(u[2]); dst[3] += b2f(u[3]);                         \
            dst[4] += b2f(u[4]); dst[5] += b2f(u[5]);                         \
            dst[6] += b2f(u[6]); dst[7] += b2f(u[7]);                         \
        }                                                                     \
    } while (0)

    int j = beg;
    for (; j + 4 <= end; j += 4) {
        int s0 = cb[j + half];
        int s1 = cb[j + 2 + half];
        ACC_ROW(a, s0);
        ACC_ROW(b, s1);
    }
    if (j + 2 <= end) {
        int s0 = cb[j + half];
        ACC_ROW(a, s0);
        j += 2;
    }
    if (j < end && half == 0) {
        int s0 = cb[j];
        ACC_ROW(b, s0);
    }
#undef ACC_ROW

#pragma unroll
    for (int i = 0; i < 8; ++i) {
        a[i] += b[i];
        a[i] += __shfl_xor(a[i], 32);
    }
    if (half == 0) {
        float s = (end > beg) ? 1.f / (float)(end - beg) : 0.f;
        us8 o;
#pragma unroll
        for (int i = 0; i < 8; ++i) o[i] = f2b(a[i] * s);
        *reinterpret_cast<us8*>(out + (size_t)n * 1024 + e * 256 + hl * 8) = o;
    }
}

// ---------------------------------------------------------------------------
// MFMA GEMM, BM=128 x BN=256 tile, BK=64, 512 threads = 8 waves (2M x 4N,
// 64x64 per wave). XOR-swizzled LDS, global_load_lds staging, bijective XCD
// block swizzle. 3 output zones by col-block (bn multiples of 256):
//   bn < split1          : nkt0 k-tiles, kt<KS from A0 else A1   -> C0
//   split1 <= bn < split2: KS  k-tiles, all from A0              -> C1
//   bn >= split2         : KS  k-tiles, all from A1              -> C2
// A rows clamped to N-1; C rows guarded.
// BIASK 1: bias0[global col]. 4: 4-mask bias0[e*256+col] via degmask bits.
// ---------------------------------------------------------------------------
template <int BIASK>
__global__ __launch_bounds__(512, 4) void gemm_mfma(
    const u16* __restrict__ A0, int lda0,
    const u16* __restrict__ A1, int lda1,
    const u16* __restrict__ Bw, int ldb,
    u16* __restrict__ C0, int ldc0, u16* __restrict__ C1, int ldc1,
    u16* __restrict__ C2, int ldc2,
    int split1, int split2, int nkt0, int KS,
    const float* __restrict__ bias0, const unsigned char* __restrict__ degmask)
{
    __shared__ u16 As[8192];     // 128 x 64 bf16 (16 KB)
    __shared__ u16 Bs2[16384];   // 256 x 64 bf16 (32 KB)

    const int gx = gridDim.x;
    const int nwg = gx * gridDim.y;
    const int lin = blockIdx.y * gx + blockIdx.x;
    const int q = nwg >> 3, r = nwg & 7;
    const int xcd = lin & 7, pos = lin >> 3;
    const int wg = (xcd < r) ? xcd * (q + 1) + pos
                             : r * (q + 1) + (xcd - r) * q + pos;
    const int by = wg / gx;
    const int bx = wg - by * gx;
    const int bm = by * 128;
    const int bn = bx * 256;

    const int tid = threadIdx.x;
    const int lane = tid & 63;
    const int wid = tid >> 6;          // 0..7
    const int wr = wid >> 2;           // 0..1 (row half)
    const int wc = wid & 3;            // 0..3 (col quarter)
    const int l15 = lane & 15;
    const int l4 = lane >> 4;

    int arow[2], achk[2];
#pragma unroll
    for (int ps = 0; ps < 2; ++ps) {
        int s = wid * 128 + ps * 64 + lane;
        arow[ps] = s >> 3;
        achk[ps] = (s & 7) ^ (arow[ps] & 7);
    }
    int brow[4], bchk[4];
#pragma unroll
    for (int ps = 0; ps < 4; ++ps) {
        int s = wid * 256 + ps * 64 + lane;
        brow[ps] = s >> 3;
        bchk[ps] = (s & 7) ^ (brow[ps] & 7);
    }

    f32x4 acc[4][4];
#pragma unroll
    for (int i = 0; i < 4; ++i)
#pragma unroll
        for (int j = 0; j < 4; ++j)
            acc[i][j] = (f32x4){0.f, 0.f, 0.f, 0.f};

    int nkt, ksel;
    if (bn < split1)      { nkt = nkt0; ksel = KS; }
    else if (bn < split2) { nkt = KS;   ksel = KS; }
    else                  { nkt = KS;   ksel = 0;  }

    for (int kt = 0; kt < nkt; ++kt) {
        const u16* Ab; int lda;
        if (kt < ksel) { Ab = A0 + (size_t)kt * 64;          lda = lda0; }
        else           { Ab = A1 + (size_t)(kt - ksel) * 64; lda = lda1; }
#pragma unroll
        for (int ps = 0; ps < 2; ++ps) {
            int rrow = bm + arow[ps];
            if (rrow > N_NODES - 1) rrow = N_NODES - 1;
            async16(Ab + (size_t)rrow * lda + achk[ps] * 8,
                    &As[(wid * 128 + ps * 64) * 8]);
        }
#pragma unroll
        for (int ps = 0; ps < 4; ++ps)
            async16(Bw + (size_t)(bn + brow[ps]) * ldb + kt * 64 + bchk[ps] * 8,
                    &Bs2[(wid * 256 + ps * 64) * 8]);
        __syncthreads();

#pragma unroll
        for (int kk = 0; kk < 2; ++kk) {
            bf16x8 a[4], b[4];
#pragma unroll
            for (int i = 0; i < 4; ++i) {
                int ar = wr * 64 + i * 16 + l15;
                a[i] = *reinterpret_cast<const bf16x8*>(
                    &As[ar * 64 + (((kk * 4 + l4) ^ (ar & 7)) << 3)]);
                int bc = wc * 64 + i * 16 + l15;
                b[i] = *reinterpret_cast<const bf16x8*>(
                    &Bs2[bc * 64 + (((kk * 4 + l4) ^ (bc & 7)) << 3)]);
            }
#pragma unroll
            for (int i = 0; i < 4; ++i)
#pragma unroll
                for (int j = 0; j < 4; ++j)
                    acc[i][j] = __builtin_amdgcn_mfma_f32_16x16x32_bf16(
                        a[i], b[j], acc[i][j], 0, 0, 0);
        }
        __syncthreads();
    }

    u16* Cw; int ldc, cb0;
    if (bn < split1)      { Cw = C0; ldc = ldc0; cb0 = bn; }
    else if (bn < split2) { Cw = C1; ldc = ldc1; cb0 = bn - split1; }
    else                  { Cw = C2; ldc = ldc2; cb0 = bn - split2; }

    float bj0[4];
    float bj4[4][4];
    if constexpr (BIASK == 4) {
#pragma unroll
        for (int e = 0; e < 4; ++e)
#pragma unroll
            for (int j = 0; j < 4; ++j)
                bj4[e][j] = bias0[e * 256 + bn + wc * 64 + j * 16 + l15];
    } else {
#pragma unroll
        for (int j = 0; j < 4; ++j)
            bj0[j] = bias0[bn + wc * 64 + j * 16 + l15];
    }
#pragma unroll
    for (int i = 0; i < 4; ++i) {
        int row0 = bm + wr * 64 + i * 16 + l4 * 4;
#pragma unroll
        for (int r2 = 0; r2 < 4; ++r2) {
            int row = row0 + r2;
            if (row < N_NODES) {
#pragma unroll
                for (int j = 0; j < 4; ++j) {
                    int col = cb0 + wc * 64 + j * 16 + l15;
                    float o = acc[i][j][r2];
                    if constexpr (BIASK == 4) {
                        int bits = degmask[row];
#pragma unroll
                        for (int e = 0; e < 4; ++e)
                            o += ((bits >> e) & 1) ? bj4[e][j] : 0.f;
                    } else {
                        o += bj0[j];
                    }
                    Cw[(size_t)row * ldc + col] = f2b(o);
                }
            }
        }
    }
}

// ---------------------------------------------------------------------------
// fused GRU cell + LayerNorm: one WAVE per node, vectorized, shuffle-only.
// HF32: old-state h read as f32 (step 0 reads x); else bf16.
// OUTM 0: bf16 state out; 1: f32 d_out.
// ---------------------------------------------------------------------------
template <int OUTM, int HF32>
__global__ __launch_bounds__(256) void gru_ln_kernel(
    const u16* __restrict__ rz, const u16* __restrict__ nin,
    const u16* __restrict__ hn, const void* __restrict__ hv,
    void* __restrict__ outv,
    const float* __restrict__ gamma, const float* __restrict__ beta)
{
    int w = threadIdx.x >> 6;
    int l = threadIdx.x & 63;
    int n = blockIdx.x * 4 + w;
    size_t b2 = (size_t)n * 512;
    size_t b1 = (size_t)n * D;

    u16 ra[4], za[4], na[4], ha[4];
    float hv4[4];
    *reinterpret_cast<ushort4*>(ra) = *reinterpret_cast<const ushort4*>(rz + b2 + l * 4);
    *reinterpret_cast<ushort4*>(za) = *reinterpret_cast<const ushort4*>(rz + b2 + 256 + l * 4);
    *reinterpret_cast<ushort4*>(na) = *reinterpret_cast<const ushort4*>(nin + b1 + l * 4);
    *reinterpret_cast<ushort4*>(ha) = *reinterpret_cast<const ushort4*>(hn + b1 + l * 4);
    if (HF32) {
        float4 v = *reinterpret_cast<const float4*>((const float*)hv + b1 + l * 4);
        hv4[0] = v.x; hv4[1] = v.y; hv4[2] = v.z; hv4[3] = v.w;
    } else {
        u16 va[4];
        *reinterpret_cast<ushort4*>(va) =
            *reinterpret_cast<const ushort4*>((const u16*)hv + b1 + l * 4);
        hv4[0] = b2f(va[0]); hv4[1] = b2f(va[1]);
        hv4[2] = b2f(va[2]); hv4[3] = b2f(va[3]);
    }

    float hnew[4];
    float s1 = 0.f, s2 = 0.f;
#pragma unroll
    for (int c = 0; c < 4; ++c) {
        float r = 1.f / (1.f + __expf(-b2f(ra[c])));
        float z = 1.f / (1.f + __expf(-b2f(za[c])));
        float xn = b2f(na[c]) + r * b2f(ha[c]);
        float nn = 2.f / (1.f + __expf(-2.f * xn)) - 1.f;   // tanh
        hnew[c] = (1.f - z) * nn + z * hv4[c];
        s1 += hnew[c];
        s2 += hnew[c] * hnew[c];
    }
#pragma unroll
    for (int o = 32; o > 0; o >>= 1) {
        s1 += __shfl_down(s1, o);
        s2 += __shfl_down(s2, o);
    }
    float sum = __shfl(s1, 0);
    float ssq = __shfl(s2, 0);
    float mu = sum * (1.f / D);
    float var = ssq * (1.f / D) - mu * mu;
    float rstd = rsqrtf(var + 1e-5f);

    float4 g = *reinterpret_cast<const float4*>(gamma + l * 4);
    float4 bt = *reinterpret_cast<const float4*>(beta + l * 4);
    float res[4];
    res[0] = (hnew[0] - mu) * rstd * g.x + bt.x;
    res[1] = (hnew[1] - mu) * rstd * g.y + bt.y;
    res[2] = (hnew[2] - mu) * rstd * g.z + bt.z;
    res[3] = (hnew[3] - mu) * rstd * g.w + bt.w;

    if (OUTM == 0) {
        ushort4 o;
        o.x = f2b(res[0]); o.y = f2b(res[1]); o.z = f2b(res[2]); o.w = f2b(res[3]);
        *reinterpret_cast<ushort4*>((u16*)outv + b1 + l * 4) = o;
    } else {
        *reinterpret_cast<float4*>((float*)outv + b1 + l * 4) =
            make_float4(res[0], res[1], res[2], res[3]);
    }
}

__global__ __launch_bounds__(256) void wsfail_kernel(float* __restrict__ out, float val, int n)
{
    int i = blockIdx.x * 256 + threadIdx.x;
    if (i < n) out[i] = val;
}

// ---------------------------------------------------------------------------
extern "C" void kernel_launch(void* const* d_in, const int* in_sizes, int n_in,
                              void* d_out, int out_size, void* d_ws, size_t ws_size,
                              hipStream_t stream)
{
    const float* x    = (const float*)d_in[0];
    const int* se[4] = {(const int*)d_in[1], (const int*)d_in[5],
                        (const int*)d_in[9], (const int*)d_in[13]};
    const int* de[4] = {(const int*)d_in[2], (const int*)d_in[6],
                        (const int*)d_in[10], (const int*)d_in[14]};
    const float* We[4] = {(const float*)d_in[3], (const float*)d_in[7],
                          (const float*)d_in[11], (const float*)d_in[15]};
    const float* be[4] = {(const float*)d_in[4], (const float*)d_in[8],
                          (const float*)d_in[12], (const float*)d_in[16]};
    const float* W_ih = (const float*)d_in[17];
    const float* W_hh = (const float*)d_in[18];
    const float* b_ih = (const float*)d_in[19];
    const float* b_hh = (const float*)d_in[20];
    const float* gamma = (const float*)d_in[21];
    const float* beta  = (const float*)d_in[22];
    float* outf = (float*)d_out;          // f32 [N,D], written at final step only

    const size_t SZ_H4 = (size_t)N_NODES * 1024 * 2;   // 102.4 MB
    const size_t SZ_H2 = (size_t)N_NODES * 512 * 2;    //  51.2 MB
    const size_t SZ_ND = (size_t)N_NODES * 256 * 2;    //  25.6 MB

    char* p = (char*)d_ws;
    u16* Hm   = (u16*)p; p += SZ_H4;                   // gather out [N,1024]
    u16* rzb  = Hm;                                    // aliases (Hm dead after agg)
    u16* ninb = (u16*)((char*)Hm + SZ_H2);
    u16* hnb  = (u16*)((char*)Hm + SZ_H2 + SZ_ND);
    u16* aggb = (u16*)p; p += SZ_ND;
    u16* h_bf = (u16*)p; p += SZ_ND;
    int* rowptr = (int*)p; p += 800016;                // 4*(N+1)*4
    int* bsum   = (int*)p; p += 3136;
    u16* colb   = (u16*)p; p += 2400000;
    u16* rank   = (u16*)p; p += 2400000;
    unsigned char* degmask = (unsigned char*)p; p += 50000;
    u16* Bfull_b = (u16*)p; p += 1048576;              // 1024x512 bf16
    u16* Bcat_b  = (u16*)p; p += 524288;               // 256x1024 bf16
    float* bfull = (float*)p; p += 4096;
    float* be4   = (float*)p; p += 4096;

    if (ws_size < (size_t)(p - (char*)d_ws)) {
        wsfail_kernel<<<(out_size + 255) / 256, 256, 0, stream>>>(
            outf, (float)(ws_size >> 20), out_size);
        return;
    }

    // ---- once per launch: weight pack + x->bf16 + CSR build ----
    hipMemsetAsync(rowptr, 0, (size_t)4 * (N_NODES + 1) * 4, stream);
    prep_kernel<<<2048, 256, 0, stream>>>(
        We[0], We[1], We[2], We[3], be[0], be[1], be[2], be[3],
        W_ih, W_hh, b_ih, b_hh, Bfull_b, Bcat_b, bfull, be4);
    xcvt_kernel<<<N_NODES * D / 4 / 256, 256, 0, stream>>>(x, h_bf);
    cnt_kernel<<<(4 * E_EDGES + 255) / 256, 256, 0, stream>>>(
        de[0], de[1], de[2], de[3], rowptr, rank);
    scan1_kernel<<<dim3(SCHUNKS, 4), 256, 0, stream>>>(rowptr, bsum);
    scan2_kernel<<<4, 256, 0, stream>>>(bsum);
    scan3_kernel<<<dim3(SCHUNKS, 4), 256, 0, stream>>>(rowptr, bsum);
    fill_csr_kernel<<<(4 * E_EDGES + 255) / 256, 256, 0, stream>>>(
        se[0], de[0], se[1], de[1], se[2], de[2], se[3], de[3],
        rowptr, rank, colb, degmask);

    const int BIG30 = 1 << 30;
    for (int step = 0; step < 3; ++step) {
        // one gather over all 4 etypes -> Hmean4 [N,1024]
        // step 0 reads x directly in f32 (extra accuracy, no dependency on xcvt)
        if (step == 0)
            gather_kernel<1><<<dim3(N_NODES / 2, 2), 256, 0, stream>>>(
                x, rowptr, colb, Hm);
        else
            gather_kernel<0><<<dim3(N_NODES / 2, 2), 256, 0, stream>>>(
                h_bf, rowptr, colb, Hm);
        // agg = Hmean4 @ Bcat1024^T + 4-masked biases   (BN=256: 1 col-block)
        gemm_mfma<4><<<dim3(1, 391), 512, 0, stream>>>(
            Hm, 1024, nullptr, 0, Bcat_b, 1024,
            aggb, 256, nullptr, 0, nullptr, 0,
            BIG30, BIG30, 16, 16, be4, degmask);
        // fused rz|nin|hn: zones [0,512) dual / [512,768) agg / [768,1024) h
        // (h-operand = h_bf: step 0 uses the xcvt'd copy of x)
        gemm_mfma<1><<<dim3(4, 391), 512, 0, stream>>>(
            aggb, 256, h_bf, 256, Bfull_b, 512,
            rzb, 512, ninb, 256, hnb, 256,
            512, 768, 8, 4, bfull, nullptr);

        // steps 0,1 -> h_bf (bf16); step 2 -> d_out (f32)
        if (step == 0)
            gru_ln_kernel<0, 1><<<N_NODES / 4, 256, 0, stream>>>(
                rzb, ninb, hnb, x, h_bf, gamma, beta);
        else if (step == 1)
            gru_ln_kernel<0, 0><<<N_NODES / 4, 256, 0, stream>>>(
                rzb, ninb, hnb, h_bf, h_bf, gamma, beta);
        else
            gru_ln_kernel<1, 0><<<N_NODES / 4, 256, 0, stream>>>(
                rzb, ninb, hnb, h_bf, outf, gamma, beta);
    }
}

// Round 15
// 787.398 us; speedup vs baseline: 1.0847x; 1.0847x over previous
//
#include <hip/hip_runtime.h>
#include <hip/hip_bf16.h>
#include <cstddef>

#define N_NODES 50000
#define E_EDGES 300000
#define D 256
#define SCHUNKS 196           // ceil(50001/256)

typedef unsigned short u16;
typedef __attribute__((ext_vector_type(8))) short bf16x8;   // 8 bf16 = 4 VGPRs
typedef __attribute__((ext_vector_type(4))) float f32x4;

__device__ __forceinline__ float b2f(u16 u) {
    return __uint_as_float(((unsigned)u) << 16);
}
__device__ __forceinline__ u16 f2b(float f) {
    __hip_bfloat16 h = __float2bfloat16(f);
    return *reinterpret_cast<u16*>(&h);
}
__device__ __forceinline__ void async16(const u16* g, u16* l) {
    __builtin_amdgcn_global_load_lds(
        (const __attribute__((address_space(1))) void*)g,
        (__attribute__((address_space(3))) void*)l, 16, 0, 0);
}

// ---------------------------------------------------------------------------
// prep: pack weights to bf16 once.
//  Bfull[j][k] (1024x512):
//    k<256 : j<768 ? W_ih[j][k] : W_hh[j-256][k]     (rz + i_n + h_n rows)
//    k>=256: j<512 ? W_hh[j][k-256] : 0
//  Bcat1024[j][k] (256x1024) = W_{k>>8}[j][k&255]
//  bfull[1024] = j<512: b_ih+b_hh; 512-767: b_ih[j]; 768-1023: b_hh[j-256]
//  be4[e*256+k] = b_e[k]
// ---------------------------------------------------------------------------
__global__ __launch_bounds__(256) void prep_kernel(
    const float* __restrict__ W0, const float* __restrict__ W1,
    const float* __restrict__ W2, const float* __restrict__ W3,
    const float* __restrict__ b0, const float* __restrict__ b1,
    const float* __restrict__ b2, const float* __restrict__ b3,
    const float* __restrict__ W_ih, const float* __restrict__ W_hh,
    const float* __restrict__ b_ih, const float* __restrict__ b_hh,
    u16* __restrict__ Bfull_b, u16* __restrict__ Bcat_b,
    float* __restrict__ bfull, float* __restrict__ be4)
{
    int t = blockIdx.x * 256 + threadIdx.x;    // [0, 524288)
    {
        int j = t >> 9, k = t & 511;
        float v;
        if (k < 256) v = (j < 768) ? W_ih[j * 256 + k] : W_hh[(j - 256) * 256 + k];
        else         v = (j < 512) ? W_hh[j * 256 + (k - 256)] : 0.f;
        Bfull_b[t] = f2b(v);
    }
    if (t < 262144) {
        int j = t >> 10, k = t & 1023;
        int e = k >> 8, kk = k & 255;
        const float* W = (e == 0) ? W0 : (e == 1) ? W1 : (e == 2) ? W2 : W3;
        Bcat_b[t] = f2b(W[j * 256 + kk]);
    }
    if (t < 1024) {
        bfull[t] = (t < 512) ? b_ih[t] + b_hh[t]
                 : (t < 768) ? b_ih[t] : b_hh[t - 256];
        int e = t >> 8, k = t & 255;
        const float* b = (e == 0) ? b0 : (e == 1) ? b1 : (e == 2) ? b2 : b3;
        be4[t] = b[k];
    }
}

// x (f32) -> h_bf (bf16) once
__global__ __launch_bounds__(256) void xcvt_kernel(
    const float* __restrict__ x, u16* __restrict__ hb)
{
    int t = blockIdx.x * 256 + threadIdx.x;      // 4-elem slot
    float4 v = *reinterpret_cast<const float4*>(x + (size_t)t * 4);
    ushort4 o;
    o.x = f2b(v.x); o.y = f2b(v.y); o.z = f2b(v.z); o.w = f2b(v.w);
    *reinterpret_cast<ushort4*>(hb + (size_t)t * 4) = o;
}

// ---------------------------------------------------------------------------
// CSR build, rank-based (one atomic pass).
// ---------------------------------------------------------------------------
__global__ __launch_bounds__(256) void cnt_kernel(
    const int* __restrict__ d0, const int* __restrict__ d1,
    const int* __restrict__ d2, const int* __restrict__ d3,
    int* __restrict__ rowptr, u16* __restrict__ rank)
{
    int i = blockIdx.x * 256 + threadIdx.x;
    if (i >= 4 * E_EDGES) return;
    int e = i / E_EDGES;
    int k = i - e * E_EDGES;
    const int* dp = (e == 0) ? d0 : (e == 1) ? d1 : (e == 2) ? d2 : d3;
    rank[i] = (u16)atomicAdd(&rowptr[e * (N_NODES + 1) + dp[k] + 1], 1);
}

__global__ __launch_bounds__(256) void scan1_kernel(
    int* __restrict__ rowptr, int* __restrict__ bsum)
{
    int e = blockIdx.y;
    int blk = blockIdx.x;
    int t = threadIdx.x;
    int idx = blk * 256 + t;
    int* rp = rowptr + e * (N_NODES + 1);
    int v = (idx <= N_NODES) ? rp[idx] : 0;
    __shared__ int s[256];
    s[t] = v;
    __syncthreads();
    for (int o = 1; o < 256; o <<= 1) {
        int u = (t >= o) ? s[t - o] : 0;
        __syncthreads();
        s[t] += u;
        __syncthreads();
    }
    if (idx <= N_NODES) rp[idx] = s[t];
    if (t == 255) bsum[e * SCHUNKS + blk] = s[255];
}

__global__ __launch_bounds__(256) void scan2_kernel(int* __restrict__ bsum)
{
    int e = blockIdx.x;
    int t = threadIdx.x;
    int v = (t < SCHUNKS) ? bsum[e * SCHUNKS + t] : 0;
    __shared__ int s[256];
    s[t] = v;
    __syncthreads();
    for (int o = 1; o < 256; o <<= 1) {
        int u = (t >= o) ? s[t - o] : 0;
        __syncthreads();
        s[t] += u;
        __syncthreads();
    }
    if (t < SCHUNKS) bsum[e * SCHUNKS + t] = s[t];
}

__global__ __launch_bounds__(256) void scan3_kernel(
    int* __restrict__ rowptr, const int* __restrict__ bsum)
{
    int e = blockIdx.y;
    int blk = blockIdx.x;
    if (blk == 0) return;
    int idx = blk * 256 + threadIdx.x;
    if (idx > N_NODES) return;
    rowptr[e * (N_NODES + 1) + idx] += bsum[e * SCHUNKS + blk - 1];
}

__global__ __launch_bounds__(256) void fill_csr_kernel(
    const int* __restrict__ s0, const int* __restrict__ d0,
    const int* __restrict__ s1, const int* __restrict__ d1,
    const int* __restrict__ s2, const int* __restrict__ d2,
    const int* __restrict__ s3, const int* __restrict__ d3,
    const int* __restrict__ rowptr, const u16* __restrict__ rank,
    u16* __restrict__ colb, unsigned char* __restrict__ degmask)
{
    int i = blockIdx.x * 256 + threadIdx.x;
    if (i >= 4 * E_EDGES) return;
    int e = i / E_EDGES;
    int k = i - e * E_EDGES;
    const int* sp = (e == 0) ? s0 : (e == 1) ? s1 : (e == 2) ? s2 : s3;
    const int* dp = (e == 0) ? d0 : (e == 1) ? d1 : (e == 2) ? d2 : d3;
    int dst = dp[k];
    int slot = rowptr[e * (N_NODES + 1) + dst] + (int)rank[i];
    colb[(size_t)e * E_EDGES + slot] = (u16)sp[k];
    if (i < N_NODES) {
        int m = 0;
#pragma unroll
        for (int ee = 0; ee < 4; ++ee) {
            const int* rp = rowptr + ee * (N_NODES + 1);
            if (rp[i + 1] > rp[i]) m |= (1 << ee);
        }
        degmask[i] = (unsigned char)m;
    }
}

// ---------------------------------------------------------------------------
// gather: Hmean4[n][e*256+c] = mean over in-edges(e) of hb[src][c]
// Full-wave-per-row (64 lanes x ushort4 = one 512B row, single coalesced
// segment -> best L2 behavior, R12-proven). 4-deep ILP.
// grid (N/2, 2); wave = (node, etype-slot).
// ---------------------------------------------------------------------------
__global__ __launch_bounds__(256) void gather_kernel(
    const u16* __restrict__ hb, const int* __restrict__ rowptr,
    const u16* __restrict__ colb, u16* __restrict__ out)
{
    int p = blockIdx.y;
    int n = blockIdx.x * 2 + (threadIdx.x >> 7);
    int el = (threadIdx.x >> 6) & 1;
    int lane = threadIdx.x & 63;
    int e = p * 2 + el;
    const int* rp = rowptr + e * (N_NODES + 1);
    int beg = rp[n], end = rp[n + 1];
    const u16* cb = colb + (size_t)e * E_EDGES;

    float4 a0 = make_float4(0.f, 0.f, 0.f, 0.f);
    float4 a1 = a0, a2 = a0, a3 = a0;
    int j = beg;
    for (; j + 4 <= end; j += 4) {
        int s0 = cb[j], s1 = cb[j + 1], s2 = cb[j + 2], s3 = cb[j + 3];
        ushort4 u0 = *reinterpret_cast<const ushort4*>(hb + (size_t)s0 * D + lane * 4);
        ushort4 u1 = *reinterpret_cast<const ushort4*>(hb + (size_t)s1 * D + lane * 4);
        ushort4 u2 = *reinterpret_cast<const ushort4*>(hb + (size_t)s2 * D + lane * 4);
        ushort4 u3 = *reinterpret_cast<const ushort4*>(hb + (size_t)s3 * D + lane * 4);
        a0.x += b2f(u0.x); a0.y += b2f(u0.y); a0.z += b2f(u0.z); a0.w += b2f(u0.w);
        a1.x += b2f(u1.x); a1.y += b2f(u1.y); a1.z += b2f(u1.z); a1.w += b2f(u1.w);
        a2.x += b2f(u2.x); a2.y += b2f(u2.y); a2.z += b2f(u2.z); a2.w += b2f(u2.w);
        a3.x += b2f(u3.x); a3.y += b2f(u3.y); a3.z += b2f(u3.z); a3.w += b2f(u3.w);
    }
    for (; j < end; ++j) {
        int s0 = cb[j];
        ushort4 u0 = *reinterpret_cast<const ushort4*>(hb + (size_t)s0 * D + lane * 4);
        a0.x += b2f(u0.x); a0.y += b2f(u0.y); a0.z += b2f(u0.z); a0.w += b2f(u0.w);
    }
    float ax = (a0.x + a1.x) + (a2.x + a3.x);
    float ay = (a0.y + a1.y) + (a2.y + a3.y);
    float az = (a0.z + a1.z) + (a2.z + a3.z);
    float aw = (a0.w + a1.w) + (a2.w + a3.w);
    float s = (end > beg) ? 1.f / (float)(end - beg) : 0.f;
    ushort4 o;
    o.x = f2b(ax * s); o.y = f2b(ay * s); o.z = f2b(az * s); o.w = f2b(aw * s);
    *reinterpret_cast<ushort4*>(out + (size_t)n * 1024 + e * 256 + lane * 4) = o;
}

// ---------------------------------------------------------------------------
// MFMA GEMM, BM=128 x BN=256 tile, BK=64, 512 threads = 8 waves (2M x 4N,
// 64x64 per wave). XOR-swizzled LDS, global_load_lds staging, bijective XCD
// block swizzle. 3 output zones by col-block (bn multiples of 256):
//   bn < split1          : nkt0 k-tiles, kt<KS from A0 else A1   -> C0
//   split1 <= bn < split2: KS  k-tiles, all from A0              -> C1
//   bn >= split2         : KS  k-tiles, all from A1              -> C2
// A rows clamped to N-1; C rows guarded.
// BIASK 1: bias0[global col]. 4: 4-mask bias0[e*256+col] via degmask bits.
// ---------------------------------------------------------------------------
template <int BIASK>
__global__ __launch_bounds__(512, 4) void gemm_mfma(
    const u16* __restrict__ A0, int lda0,
    const u16* __restrict__ A1, int lda1,
    const u16* __restrict__ Bw, int ldb,
    u16* __restrict__ C0, int ldc0, u16* __restrict__ C1, int ldc1,
    u16* __restrict__ C2, int ldc2,
    int split1, int split2, int nkt0, int KS,
    const float* __restrict__ bias0, const unsigned char* __restrict__ degmask)
{
    __shared__ u16 As[8192];     // 128 x 64 bf16 (16 KB)
    __shared__ u16 Bs2[16384];   // 256 x 64 bf16 (32 KB)

    const int gx = gridDim.x;
    const int nwg = gx * gridDim.y;
    const int lin = blockIdx.y * gx + blockIdx.x;
    const int q = nwg >> 3, r = nwg & 7;
    const int xcd = lin & 7, pos = lin >> 3;
    const int wg = (xcd < r) ? xcd * (q + 1) + pos
                             : r * (q + 1) + (xcd - r) * q + pos;
    const int by = wg / gx;
    const int bx = wg - by * gx;
    const int bm = by * 128;
    const int bn = bx * 256;

    const int tid = threadIdx.x;
    const int lane = tid & 63;
    const int wid = tid >> 6;          // 0..7
    const int wr = wid >> 2;           // 0..1 (row half)
    const int wc = wid & 3;            // 0..3 (col quarter)
    const int l15 = lane & 15;
    const int l4 = lane >> 4;

    int arow[2], achk[2];
#pragma unroll
    for (int ps = 0; ps < 2; ++ps) {
        int s = wid * 128 + ps * 64 + lane;
        arow[ps] = s >> 3;
        achk[ps] = (s & 7) ^ (arow[ps] & 7);
    }
    int brow[4], bchk[4];
#pragma unroll
    for (int ps = 0; ps < 4; ++ps) {
        int s = wid * 256 + ps * 64 + lane;
        brow[ps] = s >> 3;
        bchk[ps] = (s & 7) ^ (brow[ps] & 7);
    }

    f32x4 acc[4][4];
#pragma unroll
    for (int i = 0; i < 4; ++i)
#pragma unroll
        for (int j = 0; j < 4; ++j)
            acc[i][j] = (f32x4){0.f, 0.f, 0.f, 0.f};

    int nkt, ksel;
    if (bn < split1)      { nkt = nkt0; ksel = KS; }
    else if (bn < split2) { nkt = KS;   ksel = KS; }
    else                  { nkt = KS;   ksel = 0;  }

    for (int kt = 0; kt < nkt; ++kt) {
        const u16* Ab; int lda;
        if (kt < ksel) { Ab = A0 + (size_t)kt * 64;          lda = lda0; }
        else           { Ab = A1 + (size_t)(kt - ksel) * 64; lda = lda1; }
#pragma unroll
        for (int ps = 0; ps < 2; ++ps) {
            int rrow = bm + arow[ps];
            if (rrow > N_NODES - 1) rrow = N_NODES - 1;
            async16(Ab + (size_t)rrow * lda + achk[ps] * 8,
                    &As[(wid * 128 + ps * 64) * 8]);
        }
#pragma unroll
        for (int ps = 0; ps < 4; ++ps)
            async16(Bw + (size_t)(bn + brow[ps]) * ldb + kt * 64 + bchk[ps] * 8,
                    &Bs2[(wid * 256 + ps * 64) * 8]);
        __syncthreads();

#pragma unroll
        for (int kk = 0; kk < 2; ++kk) {
            bf16x8 a[4], b[4];
#pragma unroll
            for (int i = 0; i < 4; ++i) {
                int ar = wr * 64 + i * 16 + l15;
                a[i] = *reinterpret_cast<const bf16x8*>(
                    &As[ar * 64 + (((kk * 4 + l4) ^ (ar & 7)) << 3)]);
                int bc = wc * 64 + i * 16 + l15;
                b[i] = *reinterpret_cast<const bf16x8*>(
                    &Bs2[bc * 64 + (((kk * 4 + l4) ^ (bc & 7)) << 3)]);
            }
#pragma unroll
            for (int i = 0; i < 4; ++i)
#pragma unroll
                for (int j = 0; j < 4; ++j)
                    acc[i][j] = __builtin_amdgcn_mfma_f32_16x16x32_bf16(
                        a[i], b[j], acc[i][j], 0, 0, 0);
        }
        __syncthreads();
    }

    u16* Cw; int ldc, cb0;
    if (bn < split1)      { Cw = C0; ldc = ldc0; cb0 = bn; }
    else if (bn < split2) { Cw = C1; ldc = ldc1; cb0 = bn - split1; }
    else                  { Cw = C2; ldc = ldc2; cb0 = bn - split2; }

    float bj0[4];
    float bj4[4][4];
    if constexpr (BIASK == 4) {
#pragma unroll
        for (int e = 0; e < 4; ++e)
#pragma unroll
            for (int j = 0; j < 4; ++j)
                bj4[e][j] = bias0[e * 256 + bn + wc * 64 + j * 16 + l15];
    } else {
#pragma unroll
        for (int j = 0; j < 4; ++j)
            bj0[j] = bias0[bn + wc * 64 + j * 16 + l15];
    }
#pragma unroll
    for (int i = 0; i < 4; ++i) {
        int row0 = bm + wr * 64 + i * 16 + l4 * 4;
#pragma unroll
        for (int r2 = 0; r2 < 4; ++r2) {
            int row = row0 + r2;
            if (row < N_NODES) {
#pragma unroll
                for (int j = 0; j < 4; ++j) {
                    int col = cb0 + wc * 64 + j * 16 + l15;
                    float o = acc[i][j][r2];
                    if constexpr (BIASK == 4) {
                        int bits = degmask[row];
#pragma unroll
                        for (int e = 0; e < 4; ++e)
                            o += ((bits >> e) & 1) ? bj4[e][j] : 0.f;
                    } else {
                        o += bj0[j];
                    }
                    Cw[(size_t)row * ldc + col] = f2b(o);
                }
            }
        }
    }
}

// ---------------------------------------------------------------------------
// fused GRU cell + LayerNorm: one WAVE per node, vectorized, shuffle-only.
// ---------------------------------------------------------------------------
template <int OUTM>
__global__ __launch_bounds__(256) void gru_ln_kernel(
    const u16* __restrict__ rz, const u16* __restrict__ nin,
    const u16* __restrict__ hn, const u16* __restrict__ hb,
    void* __restrict__ outv,
    const float* __restrict__ gamma, const float* __restrict__ beta)
{
    int w = threadIdx.x >> 6;
    int l = threadIdx.x & 63;
    int n = blockIdx.x * 4 + w;
    size_t b2 = (size_t)n * 512;
    size_t b1 = (size_t)n * D;

    u16 ra[4], za[4], na[4], ha[4], va[4];
    *reinterpret_cast<ushort4*>(ra) = *reinterpret_cast<const ushort4*>(rz + b2 + l * 4);
    *reinterpret_cast<ushort4*>(za) = *reinterpret_cast<const ushort4*>(rz + b2 + 256 + l * 4);
    *reinterpret_cast<ushort4*>(na) = *reinterpret_cast<const ushort4*>(nin + b1 + l * 4);
    *reinterpret_cast<ushort4*>(ha) = *reinterpret_cast<const ushort4*>(hn + b1 + l * 4);
    *reinterpret_cast<ushort4*>(va) = *reinterpret_cast<const ushort4*>(hb + b1 + l * 4);

    float hnew[4];
    float s1 = 0.f, s2 = 0.f;
#pragma unroll
    for (int c = 0; c < 4; ++c) {
        float r = 1.f / (1.f + __expf(-b2f(ra[c])));
        float z = 1.f / (1.f + __expf(-b2f(za[c])));
        float xn = b2f(na[c]) + r * b2f(ha[c]);
        float nn = 2.f / (1.f + __expf(-2.f * xn)) - 1.f;   // tanh
        hnew[c] = (1.f - z) * nn + z * b2f(va[c]);
        s1 += hnew[c];
        s2 += hnew[c] * hnew[c];
    }
#pragma unroll
    for (int o = 32; o > 0; o >>= 1) {
        s1 += __shfl_down(s1, o);
        s2 += __shfl_down(s2, o);
    }
    float sum = __shfl(s1, 0);
    float ssq = __shfl(s2, 0);
    float mu = sum * (1.f / D);
    float var = ssq * (1.f / D) - mu * mu;
    float rstd = rsqrtf(var + 1e-5f);

    float4 g = *reinterpret_cast<const float4*>(gamma + l * 4);
    float4 bt = *reinterpret_cast<const float4*>(beta + l * 4);
    float res[4];
    res[0] = (hnew[0] - mu) * rstd * g.x + bt.x;
    res[1] = (hnew[1] - mu) * rstd * g.y + bt.y;
    res[2] = (hnew[2] - mu) * rstd * g.z + bt.z;
    res[3] = (hnew[3] - mu) * rstd * g.w + bt.w;

    if (OUTM == 0) {
        ushort4 o;
        o.x = f2b(res[0]); o.y = f2b(res[1]); o.z = f2b(res[2]); o.w = f2b(res[3]);
        *reinterpret_cast<ushort4*>((u16*)outv + b1 + l * 4) = o;
    } else {
        *reinterpret_cast<float4*>((float*)outv + b1 + l * 4) =
            make_float4(res[0], res[1], res[2], res[3]);
    }
}

__global__ __launch_bounds__(256) void wsfail_kernel(float* __restrict__ out, float val, int n)
{
    int i = blockIdx.x * 256 + threadIdx.x;
    if (i < n) out[i] = val;
}

// ---------------------------------------------------------------------------
extern "C" void kernel_launch(void* const* d_in, const int* in_sizes, int n_in,
                              void* d_out, int out_size, void* d_ws, size_t ws_size,
                              hipStream_t stream)
{
    const float* x    = (const float*)d_in[0];
    const int* se[4] = {(const int*)d_in[1], (const int*)d_in[5],
                        (const int*)d_in[9], (const int*)d_in[13]};
    const int* de[4] = {(const int*)d_in[2], (const int*)d_in[6],
                        (const int*)d_in[10], (const int*)d_in[14]};
    const float* We[4] = {(const float*)d_in[3], (const float*)d_in[7],
                          (const float*)d_in[11], (const float*)d_in[15]};
    const float* be[4] = {(const float*)d_in[4], (const float*)d_in[8],
                          (const float*)d_in[12], (const float*)d_in[16]};
    const float* W_ih = (const float*)d_in[17];
    const float* W_hh = (const float*)d_in[18];
    const float* b_ih = (const float*)d_in[19];
    const float* b_hh = (const float*)d_in[20];
    const float* gamma = (const float*)d_in[21];
    const float* beta  = (const float*)d_in[22];
    float* outf = (float*)d_out;          // f32 [N,D], written at final step only

    const size_t SZ_H4 = (size_t)N_NODES * 1024 * 2;   // 102.4 MB
    const size_t SZ_H2 = (size_t)N_NODES * 512 * 2;    //  51.2 MB
    const size_t SZ_ND = (size_t)N_NODES * 256 * 2;    //  25.6 MB

    char* p = (char*)d_ws;
    u16* Hm   = (u16*)p; p += SZ_H4;                   // gather out [N,1024]
    u16* rzb  = Hm;                                    // aliases (Hm dead after agg)
    u16* ninb = (u16*)((char*)Hm + SZ_H2);
    u16* hnb  = (u16*)((char*)Hm + SZ_H2 + SZ_ND);
    u16* aggb = (u16*)p; p += SZ_ND;
    u16* h_bf = (u16*)p; p += SZ_ND;
    int* rowptr = (int*)p; p += 800016;                // 4*(N+1)*4
    int* bsum   = (int*)p; p += 3136;
    u16* colb   = (u16*)p; p += 2400000;
    u16* rank   = (u16*)p; p += 2400000;
    unsigned char* degmask = (unsigned char*)p; p += 50000;
    u16* Bfull_b = (u16*)p; p += 1048576;              // 1024x512 bf16
    u16* Bcat_b  = (u16*)p; p += 524288;               // 256x1024 bf16
    float* bfull = (float*)p; p += 4096;
    float* be4   = (float*)p; p += 4096;

    if (ws_size < (size_t)(p - (char*)d_ws)) {
        wsfail_kernel<<<(out_size + 255) / 256, 256, 0, stream>>>(
            outf, (float)(ws_size >> 20), out_size);
        return;
    }

    // ---- once per launch: weight pack + x->bf16 + CSR build ----
    hipMemsetAsync(rowptr, 0, (size_t)4 * (N_NODES + 1) * 4, stream);
    prep_kernel<<<2048, 256, 0, stream>>>(
        We[0], We[1], We[2], We[3], be[0], be[1], be[2], be[3],
        W_ih, W_hh, b_ih, b_hh, Bfull_b, Bcat_b, bfull, be4);
    xcvt_kernel<<<N_NODES * D / 4 / 256, 256, 0, stream>>>(x, h_bf);
    cnt_kernel<<<(4 * E_EDGES + 255) / 256, 256, 0, stream>>>(
        de[0], de[1], de[2], de[3], rowptr, rank);
    scan1_kernel<<<dim3(SCHUNKS, 4), 256, 0, stream>>>(rowptr, bsum);
    scan2_kernel<<<4, 256, 0, stream>>>(bsum);
    scan3_kernel<<<dim3(SCHUNKS, 4), 256, 0, stream>>>(rowptr, bsum);
    fill_csr_kernel<<<(4 * E_EDGES + 255) / 256, 256, 0, stream>>>(
        se[0], de[0], se[1], de[1], se[2], de[2], se[3], de[3],
        rowptr, rank, colb, degmask);

    const int BIG30 = 1 << 30;
    for (int step = 0; step < 3; ++step) {
        // one gather over all 4 etypes -> Hmean4 [N,1024]
        gather_kernel<<<dim3(N_NODES / 2, 2), 256, 0, stream>>>(
            h_bf, rowptr, colb, Hm);
        // agg = Hmean4 @ Bcat1024^T + 4-masked biases   (BN=256: 1 col-block)
        gemm_mfma<4><<<dim3(1, 391), 512, 0, stream>>>(
            Hm, 1024, nullptr, 0, Bcat_b, 1024,
            aggb, 256, nullptr, 0, nullptr, 0,
            BIG30, BIG30, 16, 16, be4, degmask);
        // fused rz|nin|hn: zones [0,512) dual / [512,768) agg / [768,1024) h
        gemm_mfma<1><<<dim3(4, 391), 512, 0, stream>>>(
            aggb, 256, h_bf, 256, Bfull_b, 512,
            rzb, 512, ninb, 256, hnb, 256,
            512, 768, 8, 4, bfull, nullptr);

        // steps 0,1 -> h_bf (bf16, in-place safe); step 2 -> d_out (f32)
        if (step < 2)
            gru_ln_kernel<0><<<N_NODES / 4, 256, 0, stream>>>(
                rzb, ninb, hnb, h_bf, h_bf, gamma, beta);
        else
            gru_ln_kernel<1><<<N_NODES / 4, 256, 0, stream>>>(
                rzb, ninb, hnb, h_bf, outf, gamma, beta);
    }
}